// Round 10
// baseline (268.423 us; speedup 1.0000x reference)
//
#include <hip/hip_runtime.h>
#include <stdint.h>

#define M_DIM 4096
#define N_DIM 4096
#define K_DIM 4096
#define BM 128
#define BN 128
#define BKB 128   // K-bytes (= i8 elems) per tile
#define NKT (K_DIM / BKB)   // 32 K-tiles
#define NT 4      // gate tiles
#define TCOLS (N_DIM / NT)   // 1024 output cols per gate tile

typedef __attribute__((ext_vector_type(4))) int     int4v;  // 16 i8 = 4 VGPRs, or 4 i32 acc
typedef __attribute__((ext_vector_type(4))) float   f32x4;
typedef __attribute__((ext_vector_type(8))) uint8_t u8x8;

#define XSCALE (127.0f / 4.25f)
#define XDEQ   (4.25f / 127.0f)

// ---------------- fp32 -> i8 quantizers ----------------
__device__ __forceinline__ uint8_t q8(float v) {
    float c = fminf(fmaxf(v * XSCALE, -127.0f), 127.0f);
    return (uint8_t)(int8_t)(int)__builtin_rintf(c);
}
__device__ __forceinline__ uint8_t s8(float v) {           // exact ternary sign
    return (uint8_t)(int8_t)((v > 0.0f) - (v < 0.0f));
}

// MEASURED-BEST cvt (61 us wall: 131 MB HBM @ 2.15 TB/s, geometry-invariant
// across R1-R4 variants). Zero-fill rides free in this latency-bound stream.
__global__ __launch_bounds__(256) void cvt_i8_kernel(const float* __restrict__ x,
                                                     const float* __restrict__ w,
                                                     int8_t* __restrict__ xq,
                                                     int8_t* __restrict__ wq,
                                                     const int* __restrict__ gate,
                                                     float* __restrict__ out,
                                                     int* __restrict__ counts,
                                                     int n8each) {
    // counts zeroing: this dispatch fully precedes gate_compact on the stream.
    if (blockIdx.x == 0 && threadIdx.x < NT) counts[threadIdx.x] = 0;

    {   // zero-fill gated-off output tile-blocks: block b <-> (row,tile) pair b
        int row = blockIdx.x >> 2, t = blockIdx.x & 3;
        if (gate[row * NT + t] == 0) {
            f32x4 z = {0.f, 0.f, 0.f, 0.f};
            *(f32x4*)(out + (size_t)row * N_DIM + t * TCOLS + threadIdx.x * 4) = z;
        }
    }

    int idx = blockIdx.x * 256 + threadIdx.x;
    u8x8 o;
    if (idx < n8each) {
        const f32x4* s = (const f32x4*)x;
        f32x4 a = s[idx * 2], b = s[idx * 2 + 1];
        o[0] = q8(a[0]); o[1] = q8(a[1]); o[2] = q8(a[2]); o[3] = q8(a[3]);
        o[4] = q8(b[0]); o[5] = q8(b[1]); o[6] = q8(b[2]); o[7] = q8(b[3]);
        *(u8x8*)(xq + (size_t)idx * 8) = o;
    } else {
        int i = idx - n8each;
        const f32x4* s = (const f32x4*)w;
        f32x4 a = s[i * 2], b = s[i * 2 + 1];
        o[0] = s8(a[0]); o[1] = s8(a[1]); o[2] = s8(a[2]); o[3] = s8(a[3]);
        o[4] = s8(b[0]); o[5] = s8(b[1]); o[6] = s8(b[2]); o[7] = s8(b[3]);
        *(u8x8*)(wq + (size_t)i * 8) = o;
    }
}

// ---------------- per-tile row compaction (order-unstable) ----------------
__global__ __launch_bounds__(256) void gate_compact(const int* __restrict__ gate,
                                                    int* __restrict__ rowlist,
                                                    int* __restrict__ counts) {
    int row  = blockIdx.x * 256 + threadIdx.x;   // 4096 threads over 16 blocks
    int lane = threadIdx.x & 63;
#pragma unroll
    for (int t = 0; t < NT; ++t) {
        int pred = (gate[row * NT + t] != 0);
        unsigned long long m = __ballot(pred);
        if (m != 0) {
            int leader = __ffsll((long long)m) - 1;
            int base = 0;
            if (lane == leader) base = atomicAdd(&counts[t], (int)__popcll(m));
            base = __shfl(base, leader);
            if (pred) {
                int prefix = (int)__popcll(m & ((1ull << lane) - 1ull));
                rowlist[t * M_DIM + base + prefix] = row;
            }
        }
    }
}

// ---------------- async global->LDS, 16B per lane ----------------
__device__ __forceinline__ void gload_lds16(const int8_t* g, int8_t* l) {
    __builtin_amdgcn_global_load_lds(
        (__attribute__((address_space(1))) void*)(g),
        (__attribute__((address_space(3))) void*)(l),
        16, 0, 0);
}

// ---------------- i8 GEMM, compacted rows, 2-PHASE DOUBLE BUFFER ----------------
// T3 minimum recipe, standard primitives only (no raw barriers / hand vmcnt):
//   prologue: stage(buf0, tile0)
//   loop t:   __syncthreads()          <- drains stage(buf_cur) issued at t-1,
//                                         AFTER a full MFMA phase of overlap
//             stage(buf_cur^1, t+1)    <- issued BEFORE compute, flies under MFMAs
//             compute(buf_cur)
// Hazard audit (R9 resubmit, infra-retry):
//   WAR buf[cur^1]: barrier at top of t proves all waves' reads from t-1 done.
//   RAW buf[cur]:   __syncthreads emits vmcnt(0) drain before s_barrier.
//   Early-exit blocks return before any barrier, block-uniformly.
__global__ __launch_bounds__(256, 2) void trix_gemm(
    const int8_t* __restrict__ A,        // xq i8 [4096][4096]
    const int8_t* __restrict__ B,        // wq i8 [4096][4096] (O-major, K contig)
    const int* __restrict__ gate,        // [4096][4]
    const float* __restrict__ scales,    // [4096]
    const int* __restrict__ rowlist,     // [4][4096] compacted row ids
    const int* __restrict__ counts,      // [4]
    float* __restrict__ out)             // [4096][4096] fp32
{
    const int tile = blockIdx.x >> 3;         // 8 n-blocks per gate tile
    const int cnt  = counts[tile];
    const int m0   = blockIdx.y * BM;         // position in compacted domain
    if (m0 >= cnt) return;                    // whole block exits before barriers

    __shared__ __align__(16) int8_t As[2][BM * BKB];   // 2 x 16 KB
    __shared__ __align__(16) int8_t Bs[2][BN * BKB];   // 2 x 16 KB

    const int tid  = threadIdx.x;
    const int lane = tid & 63;
    const int wave = tid >> 6;       // 0..3
    const int wm   = wave >> 1;      // 0..1
    const int wn   = wave & 1;       // 0..1
    const int quad = lane >> 4;      // 0..3
    const int ln16 = lane & 15;

    const int n0 = blockIdx.x * BN;
    const int* rl = rowlist + tile * M_DIM;

    // ---- staging: 4 issues each for A and B per K-tile (1 KB per issue) ----
    const int srow   = lane >> 3;              // 0..7
    const int gchunk = (lane & 7) ^ srow;      // XOR swizzle in GLOBAL address
    const int8_t* a_src[4];
    const int8_t* b_src[4];
    int dsto[4];                               // offset within a buffer (wave-uniform)
#pragma unroll
    for (int j = 0; j < 4; ++j) {
        int cidx = j * 4 + wave;
        int ra = m0 + cidx * 8 + srow;
        if (ra >= cnt) ra = cnt - 1;           // clamp surplus rows
        int grow = rl[ra];
        a_src[j] = A + (size_t)grow * K_DIM + gchunk * 16;
        b_src[j] = B + (size_t)(n0 + cidx * 8 + srow) * K_DIM + gchunk * 16;
        dsto[j]  = cidx * 1024;                // 8 rows x 128 B; HW adds lane*16B
    }

    // ---- fragment read offsets (within a buffer) ----
    int a_off[4][2], b_off[4][2];
#pragma unroll
    for (int i = 0; i < 4; ++i) {
        int arow = wm * 64 + i * 16 + ln16;
        int brow = wn * 64 + i * 16 + ln16;
#pragma unroll
        for (int kk = 0; kk < 2; ++kk) {
            int ch = quad + 4 * kk;
            a_off[i][kk] = arow * 128 + ((ch ^ (arow & 7)) * 16);
            b_off[i][kk] = brow * 128 + ((ch ^ (brow & 7)) * 16);
        }
    }

    int4v acc[4][4];
#pragma unroll
    for (int i = 0; i < 4; ++i)
#pragma unroll
        for (int j = 0; j < 4; ++j)
            acc[i][j] = (int4v){0, 0, 0, 0};

    // ---- prologue: stage tile 0 into buf0 ----
#pragma unroll
    for (int j = 0; j < 4; ++j) {
        gload_lds16(a_src[j], As[0] + dsto[j]);
        gload_lds16(b_src[j], Bs[0] + dsto[j]);
        a_src[j] += BKB; b_src[j] += BKB;
    }

    for (int kt = 0; kt < NKT; ++kt) {
        const int cur = kt & 1;
        __syncthreads();   // drain + barrier: buf[cur] staged (t-1 / prologue) is ready

        if (kt + 1 < NKT) {                    // stage next tile into buf[cur^1]
#pragma unroll
            for (int j = 0; j < 4; ++j) {
                gload_lds16(a_src[j], As[cur ^ 1] + dsto[j]);
                gload_lds16(b_src[j], Bs[cur ^ 1] + dsto[j]);
                a_src[j] += BKB; b_src[j] += BKB;
            }
        }

        const int8_t* ab = As[cur];
        const int8_t* bb = Bs[cur];
#pragma unroll
        for (int kk = 0; kk < 2; ++kk) {
            int4v af[4], bf[4];
#pragma unroll
            for (int i = 0; i < 4; ++i) af[i] = *(const int4v*)(ab + a_off[i][kk]);
#pragma unroll
            for (int i = 0; i < 4; ++i) bf[i] = *(const int4v*)(bb + b_off[i][kk]);
#pragma unroll
            for (int i = 0; i < 4; ++i)
#pragma unroll
                for (int j = 0; j < 4; ++j)
                    acc[i][j] = __builtin_amdgcn_mfma_i32_16x16x64_i8(
                        af[i], bf[j], acc[i][j], 0, 0, 0);
        }
    }

    // ---- epilogue: out[grow] = acc_i32 * dq * scales[n] * gate[grow][tile] ----
    float sc[4];
#pragma unroll
    for (int j = 0; j < 4; ++j) sc[j] = scales[n0 + wn * 64 + j * 16 + ln16] * XDEQ;

#pragma unroll
    for (int i = 0; i < 4; ++i) {
        int lbase = wm * 64 + i * 16 + quad * 4;
#pragma unroll
        for (int r = 0; r < 4; ++r) {
            int lr = lbase + r;
            if (m0 + lr < cnt) {
                int grow = rl[m0 + lr];
                float g = (float)gate[grow * NT + tile];   // generality: gate may be >1
                float* orow = out + (size_t)grow * N_DIM + n0 + wn * 64 + ln16;
#pragma unroll
                for (int j = 0; j < 4; ++j)
                    orow[j * 16] = (float)acc[i][j][r] * sc[j] * g;
            }
        }
    }
}

extern "C" void kernel_launch(void* const* d_in, const int* in_sizes, int n_in,
                              void* d_out, int out_size, void* d_ws, size_t ws_size,
                              hipStream_t stream) {
    const float* x      = (const float*)d_in[0];   // [4096][4096]
    const int*   gate   = (const int*)d_in[1];     // [4096][4]
    const float* weight = (const float*)d_in[2];   // [4096][4096]
    const float* scales = (const float*)d_in[3];   // [4096]
    float* out = (float*)d_out;

    int8_t* xq = (int8_t*)d_ws;                           // 16 MB i8 x
    int8_t* wq = xq + (size_t)M_DIM * K_DIM;              // 16 MB i8 W
    int* rowlist = (int*)(wq + (size_t)N_DIM * K_DIM);    // 64 KB: 4 x 4096 row ids
    int* counts  = rowlist + NT * M_DIM;                  // 16 B

    const int n8each = M_DIM * K_DIM / 8;                 // 2M threads per array
    const int total_threads = 2 * n8each;
    cvt_i8_kernel<<<total_threads / 256, 256, 0, stream>>>(x, weight, xq, wq,
                                                           gate, out, counts, n8each);
    gate_compact<<<M_DIM / 256, 256, 0, stream>>>(gate, rowlist, counts);

    dim3 grid(N_DIM / BN, M_DIM / BM);                    // 32 x 32; ~half exit early
    trix_gemm<<<grid, 256, 0, stream>>>(xq, wq, gate, scales, rowlist, counts, out);
}

// Round 11
// 224.862 us; speedup vs baseline: 1.1937x; 1.1937x over previous
//
#include <hip/hip_runtime.h>
#include <stdint.h>

#define M_DIM 4096
#define N_DIM 4096
#define K_DIM 4096
#define BM 128
#define BN 128
#define BKB 128   // K-bytes (= i8 elems) per tile
#define NT 4      // gate tiles
#define TCOLS (N_DIM / NT)   // 1024 output cols per gate tile

typedef __attribute__((ext_vector_type(4))) int     int4v;  // 16 i8 = 4 VGPRs, or 4 i32 acc
typedef __attribute__((ext_vector_type(4))) float   f32x4;
typedef __attribute__((ext_vector_type(8))) uint8_t u8x8;

#define XSCALE (127.0f / 4.25f)
#define XDEQ   (4.25f / 127.0f)

// ---------------- fp32 -> i8 quantizers ----------------
__device__ __forceinline__ uint8_t q8(float v) {
    float c = fminf(fmaxf(v * XSCALE, -127.0f), 127.0f);
    return (uint8_t)(int8_t)(int)__builtin_rintf(c);
}
__device__ __forceinline__ uint8_t s8(float v) {           // exact ternary sign
    return (uint8_t)(int8_t)((v > 0.0f) - (v < 0.0f));
}

// MEASURED-BEST cvt (61 us wall: ~131 MB HBM @ 2.15 TB/s; geometry-invariant
// across 4 falsified variants: 16-elem ILP, lane-contiguous, max-TLP, NT hints).
// Zero-fill of gated-off output tiles rides free in this latency-bound stream.
__global__ __launch_bounds__(256) void cvt_i8_kernel(const float* __restrict__ x,
                                                     const float* __restrict__ w,
                                                     int8_t* __restrict__ xq,
                                                     int8_t* __restrict__ wq,
                                                     const int* __restrict__ gate,
                                                     float* __restrict__ out,
                                                     int* __restrict__ counts,
                                                     int n8each) {
    // counts zeroing: this dispatch fully precedes gate_compact on the stream.
    if (blockIdx.x == 0 && threadIdx.x < NT) counts[threadIdx.x] = 0;

    {   // zero-fill gated-off output tile-blocks: block b <-> (row,tile) pair b
        int row = blockIdx.x >> 2, t = blockIdx.x & 3;
        if (gate[row * NT + t] == 0) {
            f32x4 z = {0.f, 0.f, 0.f, 0.f};
            *(f32x4*)(out + (size_t)row * N_DIM + t * TCOLS + threadIdx.x * 4) = z;
        }
    }

    int idx = blockIdx.x * 256 + threadIdx.x;
    u8x8 o;
    if (idx < n8each) {
        const f32x4* s = (const f32x4*)x;
        f32x4 a = s[idx * 2], b = s[idx * 2 + 1];
        o[0] = q8(a[0]); o[1] = q8(a[1]); o[2] = q8(a[2]); o[3] = q8(a[3]);
        o[4] = q8(b[0]); o[5] = q8(b[1]); o[6] = q8(b[2]); o[7] = q8(b[3]);
        *(u8x8*)(xq + (size_t)idx * 8) = o;
    } else {
        int i = idx - n8each;
        const f32x4* s = (const f32x4*)w;
        f32x4 a = s[i * 2], b = s[i * 2 + 1];
        o[0] = s8(a[0]); o[1] = s8(a[1]); o[2] = s8(a[2]); o[3] = s8(a[3]);
        o[4] = s8(b[0]); o[5] = s8(b[1]); o[6] = s8(b[2]); o[7] = s8(b[3]);
        *(u8x8*)(wq + (size_t)i * 8) = o;
    }
}

// ---------------- per-tile row compaction (order-unstable) ----------------
__global__ __launch_bounds__(256) void gate_compact(const int* __restrict__ gate,
                                                    int* __restrict__ rowlist,
                                                    int* __restrict__ counts) {
    int row  = blockIdx.x * 256 + threadIdx.x;   // 4096 threads over 16 blocks
    int lane = threadIdx.x & 63;
#pragma unroll
    for (int t = 0; t < NT; ++t) {
        int pred = (gate[row * NT + t] != 0);
        unsigned long long m = __ballot(pred);
        if (m != 0) {
            int leader = __ffsll((long long)m) - 1;
            int base = 0;
            if (lane == leader) base = atomicAdd(&counts[t], (int)__popcll(m));
            base = __shfl(base, leader);
            if (pred) {
                int prefix = (int)__popcll(m & ((1ull << lane) - 1ull));
                rowlist[t * M_DIM + base + prefix] = row;
            }
        }
    }
}

// ---------------- async global->LDS, 16B per lane ----------------
__device__ __forceinline__ void gload_lds16(const int8_t* g, int8_t* l) {
    __builtin_amdgcn_global_load_lds(
        (__attribute__((address_space(1))) void*)(g),
        (__attribute__((address_space(3))) void*)(l),
        16, 0, 0);
}

// ---------------- i8 GEMM over the COMPACTED row domain ----------------
// MEASURED-BEST config: single-buffer 32 KB LDS, (256,2), default mapping.
// Falsified alternatives (do not revisit without NEW counter evidence):
//   - XCD remap (R4): default x-major already L2-groups panels. 38->21 MfmaUtil.
//   - zero-fill in dead blocks (R5): serialized tail, 69 us.
//   - launch_bounds(256,4) (R6): occupancy DROPPED 25->19, 91 us.
//   - 2-phase dbuf 64KB LDS (R10): 1 block/CU -> no co-resident waves to hide
//     the drain; MfmaUtil 14.6%, 97 us. Occupancy >> schedule on this tile.
//   - 8-phase 256x128 (R8): container died; also needs 96KB LDS (same cliff).
__global__ __launch_bounds__(256, 2) void trix_gemm(
    const int8_t* __restrict__ A,        // xq i8 [4096][4096]
    const int8_t* __restrict__ B,        // wq i8 [4096][4096] (O-major, K contig)
    const int* __restrict__ gate,        // [4096][4]
    const float* __restrict__ scales,    // [4096]
    const int* __restrict__ rowlist,     // [4][4096] compacted row ids
    const int* __restrict__ counts,      // [4]
    float* __restrict__ out)             // [4096][4096] fp32
{
    const int tile = blockIdx.x >> 3;         // 8 n-blocks per gate tile
    const int cnt  = counts[tile];
    const int m0   = blockIdx.y * BM;         // position in compacted domain
    if (m0 >= cnt) return;

    __shared__ __align__(16) int8_t As[BM * BKB];   // 16 KB
    __shared__ __align__(16) int8_t Bs[BN * BKB];   // 16 KB

    const int tid  = threadIdx.x;
    const int lane = tid & 63;
    const int wave = tid >> 6;       // 0..3
    const int wm   = wave >> 1;      // 0..1
    const int wn   = wave & 1;       // 0..1
    const int quad = lane >> 4;      // 0..3
    const int ln16 = lane & 15;

    const int n0 = blockIdx.x * BN;
    const int* rl = rowlist + tile * M_DIM;

    // ---- staging: 4 issues each for A and B per K-tile (1 KB per issue) ----
    const int srow   = lane >> 3;              // 0..7
    const int gchunk = (lane & 7) ^ srow;      // XOR swizzle in GLOBAL address
    const int8_t* a_src[4];
    const int8_t* b_src[4];
    int8_t* a_dst[4];
    int8_t* b_dst[4];
#pragma unroll
    for (int j = 0; j < 4; ++j) {
        int cidx = j * 4 + wave;
        int ra = m0 + cidx * 8 + srow;
        if (ra >= cnt) ra = cnt - 1;           // clamp surplus rows
        int grow = rl[ra];
        a_src[j] = A + (size_t)grow * K_DIM + gchunk * 16;
        b_src[j] = B + (size_t)(n0 + cidx * 8 + srow) * K_DIM + gchunk * 16;
        a_dst[j] = As + cidx * 1024;   // 8 rows x 128 B; HW adds lane*16B
        b_dst[j] = Bs + cidx * 1024;
    }

    // ---- fragment read addresses: lane reads 16 i8 at row, k = quad*16 + kk*64 ----
    const int8_t* a_rd[4][2];
    const int8_t* b_rd[4][2];
#pragma unroll
    for (int i = 0; i < 4; ++i) {
        int arow = wm * 64 + i * 16 + ln16;
        int brow = wn * 64 + i * 16 + ln16;
#pragma unroll
        for (int kk = 0; kk < 2; ++kk) {
            int ch = quad + 4 * kk;
            a_rd[i][kk] = As + arow * 128 + ((ch ^ (arow & 7)) * 16);
            b_rd[i][kk] = Bs + brow * 128 + ((ch ^ (brow & 7)) * 16);
        }
    }

    int4v acc[4][4];
#pragma unroll
    for (int i = 0; i < 4; ++i)
#pragma unroll
        for (int j = 0; j < 4; ++j)
            acc[i][j] = (int4v){0, 0, 0, 0};

    for (int kt = 0; kt < K_DIM; kt += BKB) {   // 32 tiles
#pragma unroll
        for (int j = 0; j < 4; ++j) {
            gload_lds16(a_src[j], a_dst[j]);
            gload_lds16(b_src[j], b_dst[j]);
        }
#pragma unroll
        for (int j = 0; j < 4; ++j) { a_src[j] += BKB; b_src[j] += BKB; }
        __syncthreads();

#pragma unroll
        for (int kk = 0; kk < 2; ++kk) {
            int4v af[4], bf[4];
#pragma unroll
            for (int i = 0; i < 4; ++i) af[i] = *(const int4v*)a_rd[i][kk];
#pragma unroll
            for (int i = 0; i < 4; ++i) bf[i] = *(const int4v*)b_rd[i][kk];
#pragma unroll
            for (int i = 0; i < 4; ++i)
#pragma unroll
                for (int j = 0; j < 4; ++j)
                    acc[i][j] = __builtin_amdgcn_mfma_i32_16x16x64_i8(
                        af[i], bf[j], acc[i][j], 0, 0, 0);
        }
        __syncthreads();
    }

    // ---- epilogue: out[grow] = acc_i32 * dq * scales[n] * gate[grow][tile] ----
    float sc[4];
#pragma unroll
    for (int j = 0; j < 4; ++j) sc[j] = scales[n0 + wn * 64 + j * 16 + ln16] * XDEQ;

#pragma unroll
    for (int i = 0; i < 4; ++i) {
        int lbase = wm * 64 + i * 16 + quad * 4;
#pragma unroll
        for (int r = 0; r < 4; ++r) {
            int lr = lbase + r;
            if (m0 + lr < cnt) {
                int grow = rl[m0 + lr];
                float g = (float)gate[grow * NT + tile];   // generality: gate may be >1
                float* orow = out + (size_t)grow * N_DIM + n0 + wn * 64 + ln16;
#pragma unroll
                for (int j = 0; j < 4; ++j)
                    orow[j * 16] = (float)acc[i][j][r] * sc[j] * g;
            }
        }
    }
}

extern "C" void kernel_launch(void* const* d_in, const int* in_sizes, int n_in,
                              void* d_out, int out_size, void* d_ws, size_t ws_size,
                              hipStream_t stream) {
    const float* x      = (const float*)d_in[0];   // [4096][4096]
    const int*   gate   = (const int*)d_in[1];     // [4096][4]
    const float* weight = (const float*)d_in[2];   // [4096][4096]
    const float* scales = (const float*)d_in[3];   // [4096]
    float* out = (float*)d_out;

    int8_t* xq = (int8_t*)d_ws;                           // 16 MB i8 x
    int8_t* wq = xq + (size_t)M_DIM * K_DIM;              // 16 MB i8 W
    int* rowlist = (int*)(wq + (size_t)N_DIM * K_DIM);    // 64 KB: 4 x 4096 row ids
    int* counts  = rowlist + NT * M_DIM;                  // 16 B

    const int n8each = M_DIM * K_DIM / 8;                 // 2M threads per array
    const int total_threads = 2 * n8each;
    cvt_i8_kernel<<<total_threads / 256, 256, 0, stream>>>(x, weight, xq, wq,
                                                           gate, out, counts, n8each);
    gate_compact<<<M_DIM / 256, 256, 0, stream>>>(gate, rowlist, counts);

    dim3 grid(N_DIM / BN, M_DIM / BM);                    // 32 x 32; ~half exit early
    trix_gemm<<<grid, 256, 0, stream>>>(xq, wq, gate, scales, rowlist, counts, out);
}